// Round 3
// baseline (1491.765 us; speedup 1.0000x reference)
//
#include <hip/hip_runtime.h>

#define EPS 1e-5f
#define BATCH 524288
#define BLK 256
#define NBLK (BATCH / BLK)   // 2048 blocks for k_lstm
#define RBLK 256             // blocks for k_reduce_x

// -------- weight-table float offsets (same layout in global ws and LDS) ----
#define OFF_IH0 0                   // 4*80   W_ih0^T [k][gate]
#define OFF_HH0 320                 // 20*80  W_hh0^T
#define OFF_IH1 1920                // 20*80  W_ih1^T
#define OFF_HH1 3520                // 20*80  W_hh1^T
#define OFF_B0  5120                // 80     b_ih0+b_hh0
#define OFF_B1  5200                // 80
#define WTOT    5280
// float4 offsets
#define F4_IH0 (OFF_IH0 / 4)
#define F4_HH0 (OFF_HH0 / 4)
#define F4_IH1 (OFF_IH1 / 4)
#define F4_HH1 (OFF_HH1 / 4)
#define F4_B0  (OFF_B0 / 4)
#define F4_B1  (OFF_B1 / 4)
// workspace offsets past the weight table
#define OFF_P1  (WTOT + 96)         // RBLK*12 partials for BN1
#define OFF_P2  (OFF_P1 + RBLK*12)  // NBLK*2 partials for BN2
#define OFF_ST  (OFF_P2 + NBLK*2)   // 16 floats: a[6], b[6], s1, s2

__device__ __forceinline__ float sigm(float x) {
    return __builtin_amdgcn_rcpf(1.0f + __expf(-x));
}
__device__ __forceinline__ float tanh_f(float x) {
    return 1.0f - 2.0f * __builtin_amdgcn_rcpf(1.0f + __expf(2.0f * x));
}
__device__ __forceinline__ float wave_reduce(float v) {
    #pragma unroll
    for (int o = 32; o; o >>= 1) v += __shfl_down(v, o, 64);
    return v;
}

// ---------------- Kernel 0: transpose weights into ws ----------------
__global__ __launch_bounds__(BLK) void k_prep(
    const float* __restrict__ Wih0, const float* __restrict__ Whh0,
    const float* __restrict__ bih0, const float* __restrict__ bhh0,
    const float* __restrict__ Wih1, const float* __restrict__ Whh1,
    const float* __restrict__ bih1, const float* __restrict__ bhh1,
    float* __restrict__ wsT) {
    int tid = threadIdx.x;
    for (int m = tid; m < 320; m += BLK) {
        int k = m / 80, g = m % 80;
        wsT[OFF_IH0 + m] = Wih0[g * 4 + k];
    }
    for (int m = tid; m < 1600; m += BLK) {
        int k = m / 80, g = m % 80;
        wsT[OFF_HH0 + m] = Whh0[g * 20 + k];
        wsT[OFF_IH1 + m] = Wih1[g * 20 + k];
        wsT[OFF_HH1 + m] = Whh1[g * 20 + k];
    }
    for (int m = tid; m < 80; m += BLK) {
        wsT[OFF_B0 + m] = bih0[m] + bhh0[m];
        wsT[OFF_B1 + m] = bih1[m] + bhh1[m];
    }
}

// ---------------- Kernel 1: per-channel sums of x (grid-stride) ----------------
__global__ __launch_bounds__(BLK) void k_reduce_x(const float* __restrict__ x,
                                                  float* __restrict__ part1) {
    float s[6], q[6];
    #pragma unroll
    for (int t = 0; t < 6; ++t) { s[t] = 0.f; q[t] = 0.f; }
    for (int b = blockIdx.x * BLK + threadIdx.x; b < BATCH; b += RBLK * BLK) {
        const float4* xp = (const float4*)(x + (size_t)b * 24);
        #pragma unroll
        for (int t = 0; t < 6; ++t) {
            float4 v = xp[t];
            s[t] += (v.x + v.y) + (v.z + v.w);
            q[t] += (v.x * v.x + v.y * v.y) + (v.z * v.z + v.w * v.w);
        }
    }
    __shared__ float red[4 * 12];
    int wid = threadIdx.x >> 6, lane = threadIdx.x & 63;
    #pragma unroll
    for (int c = 0; c < 6; ++c) {
        float rs = wave_reduce(s[c]);
        float rq = wave_reduce(q[c]);
        if (lane == 0) { red[wid * 12 + c] = rs; red[wid * 12 + 6 + c] = rq; }
    }
    __syncthreads();
    if (threadIdx.x < 12) {
        float tot = red[threadIdx.x] + red[12 + threadIdx.x] +
                    red[24 + threadIdx.x] + red[36 + threadIdx.x];
        part1[blockIdx.x * 12 + threadIdx.x] = tot;
    }
}

// ---------------- Kernel 2: finalize BN1 stats ----------------
__global__ __launch_bounds__(BLK) void k_stats1(const float* __restrict__ part1,
                                                const float* __restrict__ gamma,
                                                const float* __restrict__ beta,
                                                float* __restrict__ stats) {
    float acc[12];
    #pragma unroll
    for (int c = 0; c < 12; ++c) acc[c] = 0.f;
    for (int p = threadIdx.x; p < RBLK; p += BLK) {
        #pragma unroll
        for (int c = 0; c < 12; ++c) acc[c] += part1[p * 12 + c];
    }
    __shared__ float red[4 * 12];
    __shared__ float tot[12];
    int wid = threadIdx.x >> 6, lane = threadIdx.x & 63;
    #pragma unroll
    for (int c = 0; c < 12; ++c) {
        float r = wave_reduce(acc[c]);
        if (lane == 0) red[wid * 12 + c] = r;
    }
    __syncthreads();
    if (threadIdx.x < 12) {
        tot[threadIdx.x] = red[threadIdx.x] + red[12 + threadIdx.x] +
                           red[24 + threadIdx.x] + red[36 + threadIdx.x];
    }
    __syncthreads();
    if (threadIdx.x < 6) {
        int t = threadIdx.x;
        const float N = (float)BATCH * 4.0f;
        float mean = tot[t] / N;
        float var = tot[6 + t] / N - mean * mean;
        float inv = rsqrtf(var + EPS);
        float a = gamma[t] * inv;
        stats[t] = a;
        stats[6 + t] = beta[t] - mean * a;
    }
}

// ---------------- Kernel 3: fused BN1 + 2-layer LSTM + head dot ----------------
// Weights staged in LDS, read via broadcast ds_read_b128 (wave-uniform addr =
// conflict-free fast path, prefetch depth in VGPRs with fine-grained lgkmcnt).
// Per-lane h state in LDS stride 21 (odd -> 2 lanes/bank = free).
__global__ __launch_bounds__(BLK, 2) void k_lstm(
    const float* __restrict__ x,
    const float* __restrict__ wsT,
    const float* __restrict__ Wout,
    const float* __restrict__ stats,
    float* __restrict__ dotout, float* __restrict__ part2) {
    __shared__ __align__(16) float sWT[WTOT];   // 21120 B
    __shared__ float sH0[BLK * 21];             // 21504 B
    __shared__ float sH1[BLK * 21];             // 21504 B  (total 64128 B)

    const int tid = threadIdx.x;
    // stage weights+biases global->LDS (coalesced reads, linear writes)
    for (int m = tid; m < WTOT; m += BLK) sWT[m] = wsT[m];

    // hoist BN1 coefficients to registers (uniform -> SGPR)
    float sA[12];
    #pragma unroll
    for (int c = 0; c < 12; ++c) sA[c] = stats[c];

    const int b = blockIdx.x * BLK + tid;
    float* h0p = &sH0[tid * 21];
    float* h1p = &sH1[tid * 21];
    const float4* wf4 = (const float4*)sWT;

    float c0[20], c1[20];
    #pragma unroll
    for (int j = 0; j < 20; ++j) { c0[j] = 0.f; c1[j] = 0.f; }
    __syncthreads();
    #pragma unroll
    for (int j = 0; j < 20; ++j) { h0p[j] = 0.f; h1p[j] = 0.f; }

    const float4* xp = (const float4*)(x + (size_t)b * 24);
    float acc[80];  // gate pre-activations: [0,20)=i [20,40)=f [40,60)=g [60,80)=o

    // one 80-wide FMA against broadcast weight row (2 chunks of 10 float4)
    auto mv80 = [&](int f4base, float s) {
        #pragma unroll
        for (int h4 = 0; h4 < 2; ++h4) {
            float4 w[10];
            #pragma unroll
            for (int q = 0; q < 10; ++q) w[q] = wf4[f4base + h4 * 10 + q];
            #pragma unroll
            for (int q = 0; q < 10; ++q) {
                int j = h4 * 40 + q * 4;
                acc[j + 0] = fmaf(s, w[q].x, acc[j + 0]);
                acc[j + 1] = fmaf(s, w[q].y, acc[j + 1]);
                acc[j + 2] = fmaf(s, w[q].z, acc[j + 2]);
                acc[j + 3] = fmaf(s, w[q].w, acc[j + 3]);
            }
        }
    };

    float4 xv = xp[0];
    #pragma unroll 1
    for (int t = 0; t < 6; ++t) {
        float at = sA[t], bt = sA[6 + t];
        float xn[4];
        xn[0] = at * xv.x + bt; xn[1] = at * xv.y + bt;
        xn[2] = at * xv.z + bt; xn[3] = at * xv.w + bt;
        if (t < 5) xv = xp[t + 1];   // prefetch next timestep's x

        // ---- layer 0: acc = B0 + Wih0^T xn + Whh0^T h0 ----
        #pragma unroll
        for (int q = 0; q < 20; ++q) {
            float4 bq = wf4[F4_B0 + q];
            acc[4 * q + 0] = bq.x; acc[4 * q + 1] = bq.y;
            acc[4 * q + 2] = bq.z; acc[4 * q + 3] = bq.w;
        }
        #pragma unroll
        for (int k = 0; k < 4; ++k) mv80(F4_IH0 + k * 20, xn[k]);
        {
            float s = h0p[0];
            #pragma unroll 1
            for (int k = 0; k < 20; ++k) {
                float sn = (k < 19) ? h0p[k + 1] : 0.f;
                mv80(F4_HH0 + k * 20, s);
                s = sn;
            }
        }
        #pragma unroll
        for (int j = 0; j < 20; ++j) {
            float ii = sigm(acc[j]), ff = sigm(acc[20 + j]);
            float gg = tanh_f(acc[40 + j]), oo = sigm(acc[60 + j]);
            c0[j] = ff * c0[j] + ii * gg;
            h0p[j] = oo * tanh_f(c0[j]);
        }

        // ---- layer 1: acc = B1 + Wih1^T h0_new + Whh1^T h1 ----
        #pragma unroll
        for (int q = 0; q < 20; ++q) {
            float4 bq = wf4[F4_B1 + q];
            acc[4 * q + 0] = bq.x; acc[4 * q + 1] = bq.y;
            acc[4 * q + 2] = bq.z; acc[4 * q + 3] = bq.w;
        }
        {
            float s = h0p[0];
            #pragma unroll 1
            for (int k = 0; k < 20; ++k) {
                float sn = (k < 19) ? h0p[k + 1] : 0.f;
                mv80(F4_IH1 + k * 20, s);
                s = sn;
            }
            s = h1p[0];
            #pragma unroll 1
            for (int k = 0; k < 20; ++k) {
                float sn = (k < 19) ? h1p[k + 1] : 0.f;
                mv80(F4_HH1 + k * 20, s);
                s = sn;
            }
        }
        #pragma unroll
        for (int j = 0; j < 20; ++j) {
            float ii = sigm(acc[j]), ff = sigm(acc[20 + j]);
            float gg = tanh_f(acc[40 + j]), oo = sigm(acc[60 + j]);
            c1[j] = ff * c1[j] + ii * gg;
            h1p[j] = oo * tanh_f(c1[j]);
        }
    }

    // final h2[:,5,:]: head dot + BN2 partial sums
    float sum = 0.f, sumsq = 0.f, dot = 0.f;
    #pragma unroll
    for (int j = 0; j < 20; ++j) {
        float v = h1p[j];
        sum += v; sumsq += v * v;
        dot = fmaf(v, Wout[j], dot);   // Wout uniform -> SGPR
    }
    dotout[b] = dot;
    sum = wave_reduce(sum);
    sumsq = wave_reduce(sumsq);
    __syncthreads();                    // all waves done with sH0 -> reuse as scratch
    float* red = sH0;
    int wid = tid >> 6, lane = tid & 63;
    if (lane == 0) { red[wid] = sum; red[4 + wid] = sumsq; }
    __syncthreads();
    if (tid == 0) {
        part2[blockIdx.x * 2 + 0] = red[0] + red[1] + red[2] + red[3];
        part2[blockIdx.x * 2 + 1] = red[4] + red[5] + red[6] + red[7];
    }
}

// ---------------- Kernel 4: finalize BN2 stats -> s1, s2 ----------------
__global__ __launch_bounds__(BLK) void k_stats2(const float* __restrict__ part2,
                                                const float* __restrict__ gamma,
                                                const float* __restrict__ beta,
                                                const float* __restrict__ Wout,
                                                const float* __restrict__ bout,
                                                float* __restrict__ stats) {
    float s = 0.f, q = 0.f;
    for (int p = threadIdx.x; p < NBLK; p += BLK) {
        s += part2[2 * p]; q += part2[2 * p + 1];
    }
    __shared__ float red[8];
    s = wave_reduce(s);
    q = wave_reduce(q);
    int wid = threadIdx.x >> 6, lane = threadIdx.x & 63;
    if (lane == 0) { red[wid] = s; red[4 + wid] = q; }
    __syncthreads();
    if (threadIdx.x == 0) {
        float S = red[0] + red[1] + red[2] + red[3];
        float Q = red[4] + red[5] + red[6] + red[7];
        const float N = (float)BATCH * 20.0f;
        float m = S / N, var = Q / N - m * m;
        float inv = rsqrtf(var + EPS);
        float s1 = gamma[5] * inv;
        float sw = 0.f;
        for (int h = 0; h < 20; ++h) sw += Wout[h];
        stats[12] = s1;
        stats[13] = (beta[5] - m * s1) * sw + bout[0];
    }
}

// ---------------- Kernel 5: out = s1*dot + s2 (in place) ----------------
__global__ __launch_bounds__(BLK) void k_out(float* __restrict__ out,
                                             const float* __restrict__ stats) {
    int i = blockIdx.x * BLK + threadIdx.x;
    out[i] = stats[12] * out[i] + stats[13];
}

extern "C" void kernel_launch(void* const* d_in, const int* in_sizes, int n_in,
                              void* d_out, int out_size, void* d_ws, size_t ws_size,
                              hipStream_t stream) {
    const float* x     = (const float*)d_in[0];
    const float* gamma = (const float*)d_in[1];
    const float* beta  = (const float*)d_in[2];
    const float* Wih0  = (const float*)d_in[3];
    const float* Whh0  = (const float*)d_in[4];
    const float* bih0  = (const float*)d_in[5];
    const float* bhh0  = (const float*)d_in[6];
    const float* Wih1  = (const float*)d_in[7];
    const float* Whh1  = (const float*)d_in[8];
    const float* bih1  = (const float*)d_in[9];
    const float* bhh1  = (const float*)d_in[10];
    const float* Wout  = (const float*)d_in[11];
    const float* bout  = (const float*)d_in[12];
    float* out = (float*)d_out;
    float* ws = (float*)d_ws;

    float* part1 = ws + OFF_P1;
    float* part2 = ws + OFF_P2;
    float* stats = ws + OFF_ST;

    k_prep<<<1, BLK, 0, stream>>>(Wih0, Whh0, bih0, bhh0,
                                  Wih1, Whh1, bih1, bhh1, ws);
    k_reduce_x<<<RBLK, BLK, 0, stream>>>(x, part1);
    k_stats1<<<1, BLK, 0, stream>>>(part1, gamma, beta, stats);
    k_lstm<<<NBLK, BLK, 0, stream>>>(x, ws, Wout, stats, out, part2);
    k_stats2<<<1, BLK, 0, stream>>>(part2, gamma, beta, Wout, bout, stats);
    k_out<<<NBLK, BLK, 0, stream>>>(out, stats);
}